// Round 8
// baseline (51.724 us; speedup 1.0000x reference)
//
#include <hip/hip_runtime.h>
#include <hip/hip_bf16.h>

#define NUM_TOKENS 262144
#define NUM_EXPERTS 128
#define TOPK 8
#define NBLK 512
#define NTHR 256
#define NG 8            // generations (16-token sets) per wave; 512*4*8*16 = 262144

typedef unsigned long long u64;
typedef unsigned int u32;
typedef float __attribute__((ext_vector_type(4))) f32x4;
typedef float __attribute__((ext_vector_type(2))) f32x2;

// Compare-exchange: keep larger key in a. Keys unique -> no stability needed.
__device__ __forceinline__ void ce(u64& a, u64& b) {
    bool sw = b > a;
    u64 hi = sw ? b : a;
    u64 lo = sw ? a : b;
    a = hi; b = lo;
}

// Batcher odd-even mergesort, 8 elements, descending (19 CEs).
__device__ __forceinline__ void sort8(u64 k[8]) {
    ce(k[0],k[1]); ce(k[2],k[3]); ce(k[4],k[5]); ce(k[6],k[7]);
    ce(k[0],k[2]); ce(k[1],k[3]); ce(k[4],k[6]); ce(k[5],k[7]);
    ce(k[1],k[2]); ce(k[5],k[6]);
    ce(k[0],k[4]); ce(k[1],k[5]); ce(k[2],k[6]); ce(k[3],k[7]);
    ce(k[2],k[4]); ce(k[3],k[5]);
    ce(k[1],k[2]); ce(k[3],k[4]); ce(k[5],k[6]);
}

// Bitonic merge of a bitonic 8-seq -> sorted descending (12 CEs).
__device__ __forceinline__ void bmerge8(u64 k[8]) {
    ce(k[0],k[4]); ce(k[1],k[5]); ce(k[2],k[6]); ce(k[3],k[7]);
    ce(k[0],k[2]); ce(k[1],k[3]); ce(k[4],k[6]); ce(k[5],k[7]);
    ce(k[0],k[1]); ce(k[2],k[3]); ce(k[4],k[5]); ce(k[6],k[7]);
}

// Monotone fp32 -> u32; key = (sortable << 32) | (127 - idx). Unique keys;
// larger key == larger value, ties -> smaller expert index (lax.top_k order).
__device__ __forceinline__ u64 make_key(float v, u32 low) {
    u32 b = __float_as_uint(v);
    u32 hi = b ^ (0x80000000u | (u32)((int)b >> 31));
    return ((u64)hi << 32) | low;
}

// Direct global->LDS (16B per lane; dest = wave-uniform base + lane*16).
__device__ __forceinline__ void gload_lds16(const float* g, float* l) {
    __builtin_amdgcn_global_load_lds(
        (const __attribute__((address_space(1))) void*)g,
        (__attribute__((address_space(3))) void*)l, 16, 0, 0);
}

// Persistent pipelined version of the R7 kernel: each wave owns two 8KB LDS
// slots and streams NG=8 generations of 16 tokens through them. Counted
// vmcnt(8) keeps the next generation's loads in flight across the compute
// phase (never drain to 0 in the loop), so HBM and VALU overlap instead of
// alternating. vmcnt ledger: loads=8/gen, stores=2/gen, issue order
// [gen_i(8), st_{i-1}(2), gen_{i+1}(8)] -> vmcnt(8) always covers gen_i.
__global__ __launch_bounds__(256) void select_topk_kernel(
    const float* __restrict__ logits, float* __restrict__ out)
{
    __shared__ float lds[4][2][2048];   // per wave: 2 slots x 8KB
    const int w = threadIdx.x >> 6;
    const int l = threadIdx.x & 63;
    const int s = l & 3;
    const u32 lsw = (u32)l ^ (((u32)l >> 3) & 7u);  // staging source swizzle
    const u32 rsw = (u32)l & 7u;                    // matching read swizzle
    const u32 lowb = 127u - (u32)(s * 32);

    const int ws0 = (blockIdx.x * 4 + w) * NG;  // this wave's first token-set

    auto stage = [&](int gen, int slot) {
        const float* slab = logits + (size_t)(ws0 + gen) * (16 * NUM_EXPERTS);
        float* lb = &lds[w][slot][0];
#pragma unroll
        for (int j = 0; j < 8; ++j)
            gload_lds16(slab + (size_t)(j * 64 + lsw) * 4, lb + j * 256);
    };

    auto compute_gen = [&](int gen, int slot) {
        const float* lb = &lds[w][slot][0];
        auto rd = [&](int k) -> f32x4 {   // swizzled 16B-chunk read
            u32 p = 8u * (u32)l + ((u32)k ^ rsw);
            return *reinterpret_cast<const f32x4*>(lb + p * 4);
        };

        u64 A[8], kb[8];
        auto keys8 = [&](u64 k[8], f32x4 a, f32x4 b, u32 off) {
            k[0] = make_key(a[0], lowb - off);
            k[1] = make_key(a[1], lowb - off - 1);
            k[2] = make_key(a[2], lowb - off - 2);
            k[3] = make_key(a[3], lowb - off - 3);
            k[4] = make_key(b[0], lowb - off - 4);
            k[5] = make_key(b[1], lowb - off - 5);
            k[6] = make_key(b[2], lowb - off - 6);
            k[7] = make_key(b[3], lowb - off - 7);
        };
        auto merge_in = [&]() {  // A = sorted top-8 of (A ∪ kb)
#pragma unroll
            for (int i = 0; i < 8; ++i) {
                u64 b = kb[7 - i];
                A[i] = A[i] > b ? A[i] : b;
            }
            bmerge8(A);
        };

        keys8(A,  rd(0), rd(1), 0);  sort8(A);
        keys8(kb, rd(2), rd(3), 8);  sort8(kb); merge_in();
        keys8(kb, rd(4), rd(5), 16); sort8(kb); merge_in();
        keys8(kb, rd(6), rd(7), 24); sort8(kb); merge_in();

        // Cross-lane merge over the 4 sublanes (xor masks 1,2 stay in-group);
        // afterwards all 4 sublanes hold the identical global sorted top-8.
#pragma unroll
        for (int d = 1; d <= 2; d <<= 1) {
            u64 B[8];
#pragma unroll
            for (int i = 0; i < 8; ++i) B[i] = __shfl_xor(A[7 - i], d);
#pragma unroll
            for (int i = 0; i < 8; ++i) A[i] = A[i] > B[i] ? A[i] : B[i];
            bmerge8(A);
        }

        // Decode + softmax over the selected 8 (== renormalized top-k probs).
        float e[8];
        e[0] = 1.0f;
        float Z = 1.0f;
        const u32 hi0 = (u32)(A[0] >> 32);
        const float mx = __uint_as_float(hi0 ^ (0x80000000u | ~((u32)((int)hi0 >> 31))));
#pragma unroll
        for (int k = 1; k < 8; ++k) {
            u32 hi = (u32)(A[k] >> 32);
            float v = __uint_as_float(hi ^ (0x80000000u | ~((u32)((int)hi >> 31))));
            e[k] = __expf(v - mx);
            Z += e[k];
        }
        const float inv = 1.0f / Z;

        // Sublane s stores ranks 2s, 2s+1 (static cndmask tree).
        const bool s1 = (s & 1) != 0, s2 = (s & 2) != 0;
        u32 lA = s2 ? (s1 ? (u32)A[6] : (u32)A[4]) : (s1 ? (u32)A[2] : (u32)A[0]);
        u32 lB = s2 ? (s1 ? (u32)A[7] : (u32)A[5]) : (s1 ? (u32)A[3] : (u32)A[1]);
        float eA = s2 ? (s1 ? e[6] : e[4]) : (s1 ? e[2] : e[0]);
        float eB = s2 ? (s1 ? e[7] : e[5]) : (s1 ? e[3] : e[1]);

        const size_t t = (size_t)(ws0 + gen) * 16 + (size_t)(l >> 2);
        f32x2 sid = { (float)(int)(127u - lA), (float)(int)(127u - lB) };
        f32x2 sw  = { eA * inv, eB * inv };

        __builtin_nontemporal_store(sid,
            reinterpret_cast<f32x2*>(out) + t * 4 + s);
        __builtin_nontemporal_store(sw,
            reinterpret_cast<f32x2*>(out + (size_t)NUM_TOKENS * TOPK) + t * 4 + s);
    };

    // Prologue: fill both slots.
    stage(0, 0);
    stage(1, 1);

    // Steady state: counted vmcnt keeps one generation always in flight.
#pragma unroll 1
    for (int i = 0; i < NG - 1; ++i) {
        asm volatile("s_waitcnt vmcnt(8)" ::: "memory");
        compute_gen(i, i & 1);
        if (i + 2 < NG) stage(i + 2, i & 1);   // refill the consumed slot
    }
    // Epilogue (peeled): drain everything, compute the last generation.
    asm volatile("s_waitcnt vmcnt(0)" ::: "memory");
    compute_gen(NG - 1, (NG - 1) & 1);
}

extern "C" void kernel_launch(void* const* d_in, const int* in_sizes, int n_in,
                              void* d_out, int out_size, void* d_ws, size_t ws_size,
                              hipStream_t stream) {
    const float* logits = (const float*)d_in[0];
    float* out = (float*)d_out;
    select_topk_kernel<<<NBLK, NTHR, 0, stream>>>(logits, out);
}

// Round 9
// 45.377 us; speedup vs baseline: 1.1399x; 1.1399x over previous
//
#include <hip/hip_runtime.h>
#include <hip/hip_bf16.h>

#define NUM_TOKENS 262144
#define NUM_EXPERTS 128
#define TOPK 8
#define NTHR 256
#define NBLK 2048   // 2048*256 threads / 4 lanes-per-token * 2 gens = 262144 tokens

typedef unsigned long long u64;
typedef unsigned int u32;
typedef float __attribute__((ext_vector_type(4))) f32x4;
typedef float __attribute__((ext_vector_type(2))) f32x2;

// Compare-exchange: keep larger key in a. Keys unique -> no stability needed.
__device__ __forceinline__ void ce(u64& a, u64& b) {
    bool sw = b > a;
    u64 hi = sw ? b : a;
    u64 lo = sw ? a : b;
    a = hi; b = lo;
}

// Batcher odd-even mergesort, 8 elements, descending (19 CEs).
__device__ __forceinline__ void sort8(u64 k[8]) {
    ce(k[0],k[1]); ce(k[2],k[3]); ce(k[4],k[5]); ce(k[6],k[7]);
    ce(k[0],k[2]); ce(k[1],k[3]); ce(k[4],k[6]); ce(k[5],k[7]);
    ce(k[1],k[2]); ce(k[5],k[6]);
    ce(k[0],k[4]); ce(k[1],k[5]); ce(k[2],k[6]); ce(k[3],k[7]);
    ce(k[2],k[4]); ce(k[3],k[5]);
    ce(k[1],k[2]); ce(k[3],k[4]); ce(k[5],k[6]);
}

// Bitonic merge of a bitonic 8-seq -> sorted descending (12 CEs).
__device__ __forceinline__ void bmerge8(u64 k[8]) {
    ce(k[0],k[4]); ce(k[1],k[5]); ce(k[2],k[6]); ce(k[3],k[7]);
    ce(k[0],k[2]); ce(k[1],k[3]); ce(k[4],k[6]); ce(k[5],k[7]);
    ce(k[0],k[1]); ce(k[2],k[3]); ce(k[4],k[5]); ce(k[6],k[7]);
}

// Monotone fp32 -> u32; key = (sortable << 32) | (127 - idx). Unique keys;
// larger key == larger value, ties -> smaller expert index (lax.top_k order).
__device__ __forceinline__ u64 make_key(float v, u32 low) {
    u32 b = __float_as_uint(v);
    u32 hi = b ^ (0x80000000u | (u32)((int)b >> 31));
    return ((u64)hi << 32) | low;
}

// Straight-line 2-deep software pipeline, register buffers, no LDS.
// Each 4-lane group handles two tokens (t0, t0+16). All 16 loads are issued
// up-front; gen-1's 8 loads stay in flight across gen-0's ~2100-cycle
// compute (compiler emits counted vmcnt waits at first use). No loop-carried
// buffers (R5's spill cause), no occupancy hints (R4/R5 spill cause), no
// persistent low-occupancy grid (R8's TLP collapse).
__global__ __launch_bounds__(256) void select_topk_kernel(
    const float* __restrict__ logits, float* __restrict__ out)
{
    const int g = blockIdx.x * NTHR + threadIdx.x;
    const int q = g >> 2;          // lane-group id
    const int s = g & 3;           // sublane within token group
    const int t0 = (q >> 4) * 32 + (q & 15);   // wave covers 32 contiguous tokens
    const int t1 = t0 + 16;
    const u32 lowb = 127u - (u32)(s * 32);
    const size_t lane_off = (size_t)s * 32;

    const f32x4* p0 = reinterpret_cast<const f32x4*>(
        logits + (size_t)t0 * NUM_EXPERTS + lane_off);
    const f32x4* p1 = reinterpret_cast<const f32x4*>(
        logits + (size_t)t1 * NUM_EXPERTS + lane_off);

    f32x4 X[8], Y[8];
#pragma unroll
    for (int j = 0; j < 8; ++j) X[j] = p0[j];
#pragma unroll
    for (int j = 0; j < 8; ++j) Y[j] = p1[j];

    auto compute_and_store = [&](const f32x4 buf[8], int t) {
        u64 A[8], kb[8];
        auto keys8 = [&](u64 k[8], f32x4 a, f32x4 b, u32 off) {
            k[0] = make_key(a[0], lowb - off);
            k[1] = make_key(a[1], lowb - off - 1);
            k[2] = make_key(a[2], lowb - off - 2);
            k[3] = make_key(a[3], lowb - off - 3);
            k[4] = make_key(b[0], lowb - off - 4);
            k[5] = make_key(b[1], lowb - off - 5);
            k[6] = make_key(b[2], lowb - off - 6);
            k[7] = make_key(b[3], lowb - off - 7);
        };
        auto merge_in = [&]() {  // A = sorted top-8 of (A ∪ kb)
#pragma unroll
            for (int i = 0; i < 8; ++i) {
                u64 b = kb[7 - i];
                A[i] = A[i] > b ? A[i] : b;
            }
            bmerge8(A);
        };

        keys8(A,  buf[0], buf[1], 0);  sort8(A);
        keys8(kb, buf[2], buf[3], 8);  sort8(kb); merge_in();
        keys8(kb, buf[4], buf[5], 16); sort8(kb); merge_in();
        keys8(kb, buf[6], buf[7], 24); sort8(kb); merge_in();

        // Cross-lane merge over the 4 sublanes (xor masks 1,2 stay in-group);
        // afterwards all 4 sublanes hold the identical global sorted top-8.
#pragma unroll
        for (int d = 1; d <= 2; d <<= 1) {
            u64 B[8];
#pragma unroll
            for (int i = 0; i < 8; ++i) B[i] = __shfl_xor(A[7 - i], d);
#pragma unroll
            for (int i = 0; i < 8; ++i) A[i] = A[i] > B[i] ? A[i] : B[i];
            bmerge8(A);
        }

        // Decode + softmax over the selected 8 (== renormalized top-k probs).
        float e[8];
        e[0] = 1.0f;
        float Z = 1.0f;
        const u32 hi0 = (u32)(A[0] >> 32);
        const float mx = __uint_as_float(hi0 ^ (0x80000000u | ~((u32)((int)hi0 >> 31))));
#pragma unroll
        for (int k = 1; k < 8; ++k) {
            u32 hi = (u32)(A[k] >> 32);
            float v = __uint_as_float(hi ^ (0x80000000u | ~((u32)((int)hi >> 31))));
            e[k] = __expf(v - mx);
            Z += e[k];
        }
        const float inv = 1.0f / Z;

        // Sublane s stores ranks 2s, 2s+1 (static cndmask tree).
        const bool s1 = (s & 1) != 0, s2 = (s & 2) != 0;
        u32 lA = s2 ? (s1 ? (u32)A[6] : (u32)A[4]) : (s1 ? (u32)A[2] : (u32)A[0]);
        u32 lB = s2 ? (s1 ? (u32)A[7] : (u32)A[5]) : (s1 ? (u32)A[3] : (u32)A[1]);
        float eA = s2 ? (s1 ? e[6] : e[4]) : (s1 ? e[2] : e[0]);
        float eB = s2 ? (s1 ? e[7] : e[5]) : (s1 ? e[3] : e[1]);

        f32x2 sid = { (float)(int)(127u - lA), (float)(int)(127u - lB) };
        f32x2 sw  = { eA * inv, eB * inv };

        __builtin_nontemporal_store(sid,
            reinterpret_cast<f32x2*>(out) + (size_t)t * 4 + s);
        __builtin_nontemporal_store(sw,
            reinterpret_cast<f32x2*>(out + (size_t)NUM_TOKENS * TOPK) + (size_t)t * 4 + s);
    };

    compute_and_store(X, t0);
    compute_and_store(Y, t1);
}

extern "C" void kernel_launch(void* const* d_in, const int* in_sizes, int n_in,
                              void* d_out, int out_size, void* d_ws, size_t ws_size,
                              hipStream_t stream) {
    const float* logits = (const float*)d_in[0];
    float* out = (float*)d_out;
    select_topk_kernel<<<NBLK, NTHR, 0, stream>>>(logits, out);
}

// Round 10
// 40.817 us; speedup vs baseline: 1.2672x; 1.1117x over previous
//
#include <hip/hip_runtime.h>
#include <hip/hip_bf16.h>

#define NUM_TOKENS 262144
#define NUM_EXPERTS 128
#define TOPK 8

typedef unsigned long long u64;
typedef unsigned int u32;
typedef float __attribute__((ext_vector_type(4))) f32x4;
typedef float __attribute__((ext_vector_type(2))) f32x2;

// Compare-exchange: keep larger key in a. Keys unique -> no stability needed.
__device__ __forceinline__ void ce(u64& a, u64& b) {
    bool sw = b > a;
    u64 hi = sw ? b : a;
    u64 lo = sw ? a : b;
    a = hi; b = lo;
}

// Batcher odd-even mergesort, 8 elements, descending (19 CEs).
__device__ __forceinline__ void sort8(u64 k[8]) {
    ce(k[0],k[1]); ce(k[2],k[3]); ce(k[4],k[5]); ce(k[6],k[7]);
    ce(k[0],k[2]); ce(k[1],k[3]); ce(k[4],k[6]); ce(k[5],k[7]);
    ce(k[1],k[2]); ce(k[5],k[6]);
    ce(k[0],k[4]); ce(k[1],k[5]); ce(k[2],k[6]); ce(k[3],k[7]);
    ce(k[2],k[4]); ce(k[3],k[5]);
    ce(k[1],k[2]); ce(k[3],k[4]); ce(k[5],k[6]);
}

// Bitonic merge of a bitonic 8-seq -> sorted descending (12 CEs).
__device__ __forceinline__ void bmerge8(u64 k[8]) {
    ce(k[0],k[4]); ce(k[1],k[5]); ce(k[2],k[6]); ce(k[3],k[7]);
    ce(k[0],k[2]); ce(k[1],k[3]); ce(k[4],k[6]); ce(k[5],k[7]);
    ce(k[0],k[1]); ce(k[2],k[3]); ce(k[4],k[5]); ce(k[6],k[7]);
}

// Monotone fp32 -> u32; key = (sortable << 32) | (127 - idx). Unique keys;
// larger key == larger value, ties -> smaller expert index (lax.top_k order).
__device__ __forceinline__ u64 make_key(float v, u32 low) {
    u32 b = __float_as_uint(v);
    u32 hi = b ^ (0x80000000u | (u32)((int)b >> 31));
    return ((u64)hi << 32) | low;
}

// Direct global->LDS (16B per lane; dest = uniform base + lane*16).
__device__ __forceinline__ void gload_lds16(const float* g, float* l) {
    __builtin_amdgcn_global_load_lds(
        (const __attribute__((address_space(1))) void*)g,
        (__attribute__((address_space(3))) void*)l, 16, 0, 0);
}

// Best-known structure (R7, 40.9 us ~= read-BW roofline): each wave stages
// 16 tokens (8KB) coalesced into its private LDS slice via global_load_lds
// (unit-stride lines), then 4 lanes/token consume 128B rows from LDS.
// Source addresses pre-swizzled (chunk ^= (lane>>3)&7, involution) so the
// strided LDS reads are <=2-way bank-conflicted (free per m136).
// Wave-private slices -> no __syncthreads, only vmcnt(0).
// Effective read rate ~3.7 TB/s == measured streaming-read ceiling on gfx950
// (m13 copy read-half ~3.15 TB/s; write-only fills 7.1 TB/s).
__global__ __launch_bounds__(256) void select_topk_kernel(
    const float* __restrict__ logits, float* __restrict__ out)
{
    __shared__ float lds[4][2048];   // 8KB per wave
    const int w = threadIdx.x >> 6;
    const int l = threadIdx.x & 63;

    const int wave_tok0 = blockIdx.x * 64 + w * 16;
    const float* slab = logits + (size_t)wave_tok0 * NUM_EXPERTS;
    float* lb = &lds[w][0];

    // Stage: LDS 16B-chunk (j*64 + l) receives global chunk (j*64 + swz(l)).
    const u32 lsw = (u32)l ^ (((u32)l >> 3) & 7u);
#pragma unroll
    for (int j = 0; j < 8; ++j)
        gload_lds16(slab + (size_t)(j * 64 + lsw) * 4, lb + j * 256);
    asm volatile("s_waitcnt vmcnt(0)" ::: "memory");

    // Lane l: token wave_tok0+(l>>2), sublane s=l&3 owns experts s*32..s*32+31
    // = within-wave chunks 8l..8l+7, stored at LDS chunk 8l + (k ^ (l&7)).
    const int s = l & 3;
    const u32 rsw = (u32)l & 7u;
    const u32 lowb = 127u - (u32)(s * 32);

    u64 A[8], kb[8];
    auto keys8 = [&](u64 k[8], f32x4 a, f32x4 b, u32 off) {
        k[0] = make_key(a[0], lowb - off);
        k[1] = make_key(a[1], lowb - off - 1);
        k[2] = make_key(a[2], lowb - off - 2);
        k[3] = make_key(a[3], lowb - off - 3);
        k[4] = make_key(b[0], lowb - off - 4);
        k[5] = make_key(b[1], lowb - off - 5);
        k[6] = make_key(b[2], lowb - off - 6);
        k[7] = make_key(b[3], lowb - off - 7);
    };
    auto merge_in = [&]() {  // A = sorted top-8 of (A ∪ kb)
#pragma unroll
        for (int i = 0; i < 8; ++i) {
            u64 b = kb[7 - i];
            A[i] = A[i] > b ? A[i] : b;
        }
        bmerge8(A);
    };
    auto rd = [&](int k) -> f32x4 {
        u32 p = 8u * (u32)l + ((u32)k ^ rsw);    // swizzled 16B-chunk index
        return *reinterpret_cast<const f32x4*>(lb + p * 4);
    };

    keys8(A,  rd(0), rd(1), 0);  sort8(A);
    keys8(kb, rd(2), rd(3), 8);  sort8(kb); merge_in();
    keys8(kb, rd(4), rd(5), 16); sort8(kb); merge_in();
    keys8(kb, rd(6), rd(7), 24); sort8(kb); merge_in();

    // Cross-lane merge across the 4 sublanes (xor masks 1,2 stay in-group).
    // Afterwards all 4 sublanes hold the identical global sorted top-8.
#pragma unroll
    for (int d = 1; d <= 2; d <<= 1) {
        u64 B[8];
#pragma unroll
        for (int i = 0; i < 8; ++i) B[i] = __shfl_xor(A[7 - i], d);
#pragma unroll
        for (int i = 0; i < 8; ++i) A[i] = A[i] > B[i] ? A[i] : B[i];
        bmerge8(A);
    }

    // Decode + softmax over the selected 8 (== renormalized top-k probs).
    float e[8];
    e[0] = 1.0f;
    float Z = 1.0f;
    const u32 hi0 = (u32)(A[0] >> 32);
    const float mx = __uint_as_float(hi0 ^ (0x80000000u | ~((u32)((int)hi0 >> 31))));
#pragma unroll
    for (int k = 1; k < 8; ++k) {
        u32 hi = (u32)(A[k] >> 32);
        float v = __uint_as_float(hi ^ (0x80000000u | ~((u32)((int)hi >> 31))));
        e[k] = __expf(v - mx);
        Z += e[k];
    }
    const float inv = 1.0f / Z;

    // Sublane s stores ranks 2s, 2s+1 (static cndmask tree).
    const bool s1 = (s & 1) != 0, s2 = (s & 2) != 0;
    u32 lA = s2 ? (s1 ? (u32)A[6] : (u32)A[4]) : (s1 ? (u32)A[2] : (u32)A[0]);
    u32 lB = s2 ? (s1 ? (u32)A[7] : (u32)A[5]) : (s1 ? (u32)A[3] : (u32)A[1]);
    float eA = s2 ? (s1 ? e[6] : e[4]) : (s1 ? e[2] : e[0]);
    float eB = s2 ? (s1 ? e[7] : e[5]) : (s1 ? e[3] : e[1]);

    const size_t t = (size_t)(wave_tok0 + (l >> 2));
    f32x2 sid = { (float)(int)(127u - lA), (float)(int)(127u - lB) };
    f32x2 sw  = { eA * inv, eB * inv };

    __builtin_nontemporal_store(sid,
        reinterpret_cast<f32x2*>(out) + t * 4 + s);
    __builtin_nontemporal_store(sw,
        reinterpret_cast<f32x2*>(out + (size_t)NUM_TOKENS * TOPK) + t * 4 + s);
}

extern "C" void kernel_launch(void* const* d_in, const int* in_sizes, int n_in,
                              void* d_out, int out_size, void* d_ws, size_t ws_size,
                              hipStream_t stream) {
    const float* logits = (const float*)d_in[0];
    float* out = (float*)d_out;
    select_topk_kernel<<<NUM_TOKENS / 64, 256, 0, stream>>>(logits, out);
}